// Round 2
// baseline (189.778 us; speedup 1.0000x reference)
//
#include <hip/hip_runtime.h>
#include <hip/hip_bf16.h>

#define BATCH 16384
#define FIN   768
#define FOUT  512

#define BM 128
#define BN 128
#define BK 32
#define LDK 40   // BK + 8 bf16 elems padded stride (80 B): 2-way-only LDS conflicts, keeps 16B align

typedef __attribute__((ext_vector_type(8))) short short8;
typedef __attribute__((ext_vector_type(4))) float floatx4;

// fp32 -> bf16 round-to-nearest-even
__device__ __forceinline__ unsigned short f2bf(float f) {
    union { float f; unsigned int u; } c;
    c.f = f;
    unsigned int u = c.u;
    u += 0x7fffu + ((u >> 16) & 1u);
    return (unsigned short)(u >> 16);
}

// One block: 128 rows (one perspective) x 128 features, K-loop over 768.
// Epilogue: h = clip(acc + b1, 0, 1); partial = sum_cols h * W2[p*512+col];
// quad-local shuffle reduce -> atomicAdd into ws[batch_row].
__global__ __launch_bounds__(256) void pn_gemm(
    const float* __restrict__ stm, const float* __restrict__ nstm,
    const float* __restrict__ W1, const float* __restrict__ b1,
    const float* __restrict__ W2, float* __restrict__ ws)
{
    __shared__ __align__(16) unsigned short As[BM * LDK];
    __shared__ __align__(16) unsigned short Bs[BN * LDK];

    const int tid  = threadIdx.x;
    const int lane = tid & 63;
    const int wave = tid >> 6;
    const int wm   = wave >> 1;   // wave row-half (0..1)
    const int wn   = wave & 1;    // wave col-half (0..1)
    const int quad = lane >> 4;   // 0..3
    const int l16  = lane & 15;

    const int rowTile = blockIdx.y * BM;   // 0..32640, multiple of 128
    const int colTile = blockIdx.x * BN;   // 0,128,256,384

    const int p = (rowTile >= BATCH) ? 1 : 0;
    const float* __restrict__ X = p ? nstm : stm;
    const int rowOff = rowTile - p * BATCH;   // row within this perspective's batch

    floatx4 acc[4][4];
    #pragma unroll
    for (int i = 0; i < 4; ++i)
        #pragma unroll
        for (int j = 0; j < 4; ++j)
            acc[i][j] = (floatx4)0.0f;

    for (int kt = 0; kt < FIN; kt += BK) {
        __syncthreads();
        // stage A: 128 rows x 32 k (fp32 -> bf16). 1024 float4s over 256 threads.
        #pragma unroll
        for (int i = 0; i < 4; ++i) {
            int idx = tid + i * 256;
            int row = idx >> 3;       // 0..127
            int p4  = idx & 7;        // 0..7 float4 within the 32-k chunk
            const float4 v = *(const float4*)(X + (size_t)(rowOff + row) * FIN + kt + p4 * 4);
            ushort4 o;
            o.x = f2bf(v.x); o.y = f2bf(v.y); o.z = f2bf(v.z); o.w = f2bf(v.w);
            *(ushort4*)(&As[row * LDK + p4 * 4]) = o;
        }
        // stage B: W1 rows (features) x 32 k
        #pragma unroll
        for (int i = 0; i < 4; ++i) {
            int idx = tid + i * 256;
            int row = idx >> 3;
            int p4  = idx & 7;
            const float4 v = *(const float4*)(W1 + (size_t)(colTile + row) * FIN + kt + p4 * 4);
            ushort4 o;
            o.x = f2bf(v.x); o.y = f2bf(v.y); o.z = f2bf(v.z); o.w = f2bf(v.w);
            *(ushort4*)(&Bs[row * LDK + p4 * 4]) = o;
        }
        __syncthreads();

        // A frag: A[m=lane&15][k=quad*8+j]; B frag: B-col n=lane&15, k=quad*8+j = W1[n][k]
        short8 af[4], bfr[4];
        #pragma unroll
        for (int mi = 0; mi < 4; ++mi)
            af[mi] = *(const short8*)(&As[(wm * 64 + mi * 16 + l16) * LDK + quad * 8]);
        #pragma unroll
        for (int ni = 0; ni < 4; ++ni)
            bfr[ni] = *(const short8*)(&Bs[(wn * 64 + ni * 16 + l16) * LDK + quad * 8]);

        #pragma unroll
        for (int mi = 0; mi < 4; ++mi)
            #pragma unroll
            for (int ni = 0; ni < 4; ++ni)
                acc[mi][ni] = __builtin_amdgcn_mfma_f32_16x16x32_bf16(
                    af[mi], bfr[ni], acc[mi][ni], 0, 0, 0);
    }

    // epilogue: C/D layout col = lane&15, row = quad*4 + reg
    float b1v[4], w2v[4];
    #pragma unroll
    for (int ni = 0; ni < 4; ++ni) {
        int col = colTile + wn * 64 + ni * 16 + l16;
        b1v[ni] = b1[col];
        w2v[ni] = W2[p * FOUT + col];
    }

    const int rBase = rowOff + wm * 64;
    #pragma unroll
    for (int mi = 0; mi < 4; ++mi) {
        #pragma unroll
        for (int r = 0; r < 4; ++r) {
            float s = 0.0f;
            #pragma unroll
            for (int ni = 0; ni < 4; ++ni) {
                float h = acc[mi][ni][r] + b1v[ni];
                h = fminf(fmaxf(h, 0.0f), 1.0f);
                s += h * w2v[ni];
            }
            // reduce across the 16 lanes of this quad (distinct cols, same row)
            s += __shfl_xor(s, 1);
            s += __shfl_xor(s, 2);
            s += __shfl_xor(s, 4);
            s += __shfl_xor(s, 8);
            if (l16 == 0) {
                atomicAdd(&ws[rBase + mi * 16 + quad * 4 + r], s);
            }
        }
    }
}

__global__ __launch_bounds__(256) void pn_finalize(
    const float* __restrict__ ws, const float* __restrict__ b2,
    float* __restrict__ out)
{
    int i = blockIdx.x * blockDim.x + threadIdx.x;
    float x = ws[i] + b2[0];
    out[i] = 1.0f / (1.0f + expf(-x));
}

extern "C" void kernel_launch(void* const* d_in, const int* in_sizes, int n_in,
                              void* d_out, int out_size, void* d_ws, size_t ws_size,
                              hipStream_t stream)
{
    (void)in_sizes; (void)n_in; (void)out_size; (void)ws_size;
    const float* stm  = (const float*)d_in[0];
    const float* nstm = (const float*)d_in[1];
    const float* W1   = (const float*)d_in[2];
    const float* b1   = (const float*)d_in[3];
    const float* W2   = (const float*)d_in[4];
    const float* b2   = (const float*)d_in[5];
    float* out = (float*)d_out;
    float* ws  = (float*)d_ws;

    // zero the per-row partial accumulators (ws is poisoned before every launch)
    hipMemsetAsync(ws, 0, BATCH * sizeof(float), stream);

    dim3 grid(FOUT / BN, (2 * BATCH) / BM);   // (4, 256) = 1024 blocks
    pn_gemm<<<grid, dim3(256), 0, stream>>>(stm, nstm, W1, b1, W2, ws);
    pn_finalize<<<dim3(BATCH / 256), dim3(256), 0, stream>>>(ws, b2, out);
}